// Round 11
// baseline (257.627 us; speedup 1.0000x reference)
//
#include <hip/hip_runtime.h>

#define NN 100000
#define NE 1600000
#define NTOT (NN + NE)
#define NB 782            // buckets of 128 dst nodes
#define ACHUNK 2048       // edges per chunk (hist/scatA block)
#define NCH 782           // ceil(NE/ACHUNK)
#define BCAP 3072         // phase-B LDS col capacity

typedef __attribute__((ext_vector_type(8))) short bf16x8;
typedef __attribute__((ext_vector_type(4))) float f32x4;

static __device__ __forceinline__ float blo(unsigned int u) {
  union { unsigned int i; float f; } v; v.i = u << 16; return v.f;
}
static __device__ __forceinline__ float bhi(unsigned int u) {
  union { unsigned int i; float f; } v; v.i = u & 0xffff0000u; return v.f;
}
static __device__ __forceinline__ unsigned short f2bf(float f) {
  union { float f; unsigned int i; } v; v.f = f;
  unsigned int i = v.i;
  i += 0x7fffu + ((i >> 16) & 1u);
  return (unsigned short)(i >> 16);
}

// ---------------- CSR build: atomic-free two-phase counting sort ----------------
__global__ __launch_bounds__(512) void kb_hist(const int* __restrict__ ei,
                                               int* __restrict__ cntMat) {
  __shared__ int h[NB];
  int tid = threadIdx.x, blk = blockIdx.x;
  int e0 = blk * ACHUNK;
  int n = min(ACHUNK, NE - e0);
  for (int i = tid; i < NB; i += 512) h[i] = 0;
  __syncthreads();
  for (int i = tid; i < n; i += 512) atomicAdd(&h[ei[NE + e0 + i] >> 7], 1);
  __syncthreads();
  for (int i = tid; i < NB; i += 512) cntMat[blk * NB + i] = h[i];
}

__global__ void kb_colscan(int* __restrict__ cntMat, int* __restrict__ bucketCnt) {
  int b = blockIdx.x;
  int lane = threadIdx.x;  // 64
  int carry = 0;
  for (int base = 0; base < NCH; base += 64) {
    int idx = base + lane;
    int v = (idx < NCH) ? cntMat[idx * NB + b] : 0;
    int x = v;
#pragma unroll
    for (int d = 1; d < 64; d <<= 1) {
      int y = __shfl_up(x, d, 64);
      if (lane >= d) x += y;
    }
    if (idx < NCH) cntMat[idx * NB + b] = carry + x - v;  // exclusive within column
    carry += __shfl(x, 63, 64);
  }
  if (lane == 0) bucketCnt[b] = carry;
}

__global__ void kb_scan(const int* __restrict__ bucketCnt, int* __restrict__ pairOffset) {
  int lane = threadIdx.x;  // 64 threads, 13 chunks each
  int c[13];
  int run = 0;
  int idx0 = lane * 13;
#pragma unroll
  for (int k = 0; k < 13; ++k) {
    int idx = idx0 + k;
    int v = (idx < NB) ? bucketCnt[idx] : 0;
    c[k] = run;
    run += v;
  }
  int x = run;
#pragma unroll
  for (int d = 1; d < 64; d <<= 1) {
    int y = __shfl_up(x, d, 64);
    if (lane >= d) x += y;
  }
  int laneoff = x - run;
#pragma unroll
  for (int k = 0; k < 13; ++k) {
    int idx = idx0 + k;
    if (idx <= NB) pairOffset[idx] = laneoff + c[k];
  }
}

__global__ __launch_bounds__(512) void kb_scatA(const int* __restrict__ ei,
                                                const int* __restrict__ pairOffset,
                                                const int* __restrict__ cntMat,
                                                int* __restrict__ pair) {
  __shared__ int lcnt[NB + 1];
  __shared__ int gbase[NB];
  __shared__ int lcur[NB];
  __shared__ int stage[ACHUNK];
  int tid = threadIdx.x, blk = blockIdx.x;
  int e0 = blk * ACHUNK;
  int n = min(ACHUNK, NE - e0);
  for (int i = tid; i <= NB; i += 512) lcnt[i] = 0;
  __syncthreads();
  for (int i = tid; i < n; i += 512) atomicAdd(&lcnt[ei[NE + e0 + i] >> 7], 1);
  __syncthreads();
  if (tid < 64) {
    int c[13];
    int run = 0;
    int idx0 = tid * 13;
#pragma unroll
    for (int k = 0; k < 13; ++k) {
      int idx = idx0 + k;
      int v = (idx < NB) ? lcnt[idx] : 0;
      c[k] = run;
      run += v;
    }
    int x = run;
#pragma unroll
    for (int d = 1; d < 64; d <<= 1) {
      int y = __shfl_up(x, d, 64);
      if (tid >= d) x += y;
    }
    int laneoff = x - run;
#pragma unroll
    for (int k = 0; k < 13; ++k) {
      int idx = idx0 + k;
      if (idx <= NB) lcnt[idx] = laneoff + c[k];
    }
  }
  __syncthreads();
  for (int b = tid; b < NB; b += 512) {
    gbase[b] = pairOffset[b] + cntMat[blk * NB + b];  // no global atomics
    lcur[b] = lcnt[b];
  }
  __syncthreads();
  for (int i = tid; i < n; i += 512) {
    int s = ei[e0 + i], d = ei[NE + e0 + i];
    int b = d >> 7;
    int p = atomicAdd(&lcur[b], 1);   // LDS only
    stage[p] = (s << 7) | (d & 127);
  }
  __syncthreads();
  for (int b = tid; b < NB; b += 512) {
    int base = lcnt[b], cnt = lcnt[b + 1] - base, g = gbase[b];
    for (int k = 0; k < cnt; ++k) pair[g + k] = stage[base + k];
  }
}

__global__ __launch_bounds__(256) void kb_binB(const int* __restrict__ pair,
                                               const int* __restrict__ pairOffset,
                                               int* __restrict__ rowptr,
                                               int* __restrict__ col) {
  __shared__ int cnt[128];
  __shared__ int cur[128];
  __shared__ int stage[BCAP];
  int tid = threadIdx.x;
  int b = blockIdx.x;
  int dbase = b << 7;
  int nd = min(128, NN - dbase);
  int pbeg = pairOffset[b], m = pairOffset[b + 1] - pbeg;
  int cbase = pbeg + dbase;
  if (tid < 128) cnt[tid] = 0;
  __syncthreads();
  for (int i = tid; i < m; i += 256) atomicAdd(&cnt[pair[pbeg + i] & 127], 1);
  __syncthreads();
  if (tid < 64) {
    int i0 = 2 * tid, i1 = 2 * tid + 1;
    int v0 = cnt[i0] + (i0 < nd ? 1 : 0);
    int v1 = cnt[i1] + (i1 < nd ? 1 : 0);
    int run = v0 + v1;
    int x = run;
#pragma unroll
    for (int d = 1; d < 64; d <<= 1) {
      int y = __shfl_up(x, d, 64);
      if (tid >= d) x += y;
    }
    int e0 = x - run;
    int e1 = e0 + v0;
    if (i0 < nd) { rowptr[dbase + i0] = cbase + e0; stage[e0] = dbase + i0; cur[i0] = e0 + 1; }
    else cur[i0] = e0;
    if (i1 < nd) { rowptr[dbase + i1] = cbase + e1; stage[e1] = dbase + i1; cur[i1] = e1 + 1; }
    else cur[i1] = e1;
  }
  if (b == NB - 1 && tid == 0) rowptr[NN] = NTOT;
  __syncthreads();
  for (int i = tid; i < m; i += 256) {
    int p = pair[pbeg + i];
    int pos = atomicAdd(&cur[p & 127], 1);
    stage[pos] = p >> 7;
  }
  __syncthreads();
  int tot = m + nd;
  for (int i = tid; i < tot; i += 256) col[cbase + i] = stage[i];
}

// ------- W1 hi/lo bf16 split + FRAGMENT-MAJOR repack (coalesced gemm loads) -------
// packed index: ((ot*4 + c)*64 + quad*16 + r16)*8 + j  for W[row=ot*16+r16][k=c*32+quad*8+j]
__global__ void k_cvtW(const float* __restrict__ W1, unsigned short* __restrict__ Whp,
                       unsigned short* __restrict__ Wlp) {
  int i = blockIdx.x * 256 + threadIdx.x;
  if (i < 128 * 128) {
    int row = i >> 7, k = i & 127;
    int ot = row >> 4, r16 = row & 15;
    int c = k >> 5, quad = (k >> 3) & 3, j = k & 7;
    int dst = ((ot * 4 + c) * 64 + quad * 16 + r16) * 8 + j;
    float v = W1[i];
    unsigned short h = f2bf(v);
    Whp[dst] = h;
    Wlp[dst] = f2bf(v - blo((unsigned int)h));
  }
}

// ------- Layer 1 GEMM, operand-swapped: A=W (packed, coalesced), B=x (LDS tile) -------
// D[m=out-channel][n=node]: col=lane&15 -> node, row=quad*4+reg -> channel ot*16+quad*4+r
__global__ __launch_bounds__(256, 5) void k_gemm1(
    const float* __restrict__ x, const unsigned short* __restrict__ Whp,
    const unsigned short* __restrict__ Wlp, const float* __restrict__ asrc,
    const float* __restrict__ adst, unsigned short* __restrict__ h1b,
    float4* __restrict__ as1, float4* __restrict__ ad1) {
  __shared__ float xs[4][16 * 129];   // per-wave 16x128 tile, row stride 129
  int wid = threadIdx.x >> 6, lane = threadIdx.x & 63;
  int tile = blockIdx.x * 4 + wid;
  if (tile >= NN / 16) tile = NN / 16 - 1;  // clamp: duplicate work, benign
  int r16 = lane & 15, quad = lane >> 4;
  // cooperative coalesced x load: 8 float4 instrs, 2 rows (1KB) per instr
  const float4* xg = (const float4*)(x + (size_t)tile * 16 * 128);
  {
    int half = lane >> 5, l32 = lane & 31;
#pragma unroll
    for (int i = 0; i < 8; ++i) {
      int row = i * 2 + half;
      float4 v = xg[row * 32 + l32];
      float* dp = &xs[wid][row * 129 + l32 * 4];
      dp[0] = v.x; dp[1] = v.y; dp[2] = v.z; dp[3] = v.w;
    }
  }
  // B fragments (x): lane n=r16 holds k = c*32 + quad*8 + j, hi/lo truncation split
  bf16x8 bh[4], bl[4];
  const float* xr = &xs[wid][r16 * 129 + quad * 8];
#pragma unroll
  for (int c = 0; c < 4; ++c) {
#pragma unroll
    for (int j = 0; j < 8; ++j) {
      float v = xr[c * 32 + j];
      union { float f; unsigned int i; } u; u.f = v;
      bh[c][j] = (short)(u.i >> 16);
      union { float f; unsigned int i; } l; l.f = v - bhi(u.i);
      bl[c][j] = (short)(l.i >> 16);
    }
  }
  float asp[4] = {0.f, 0.f, 0.f, 0.f};   // per-head attention partials (this lane's channels)
  float adp[4] = {0.f, 0.f, 0.f, 0.f};
  int node = tile * 16 + r16;
#pragma unroll
  for (int ot = 0; ot < 8; ++ot) {
    f32x4 acc = {0.f, 0.f, 0.f, 0.f};
#pragma unroll
    for (int c = 0; c < 4; ++c) {
      // A (W): coalesced lane*16B within the 1KB fragment block
      const bf16x8 wh = *(const bf16x8*)(Whp + ((size_t)(ot * 4 + c) * 64 + lane) * 8);
      const bf16x8 wl = *(const bf16x8*)(Wlp + ((size_t)(ot * 4 + c) * 64 + lane) * 8);
      acc = __builtin_amdgcn_mfma_f32_16x16x32_bf16(wh, bh[c], acc, 0, 0, 0);
      acc = __builtin_amdgcn_mfma_f32_16x16x32_bf16(wl, bh[c], acc, 0, 0, 0);
      acc = __builtin_amdgcn_mfma_f32_16x16x32_bf16(wh, bl[c], acc, 0, 0, 0);
    }
    // channels oc = ot*16 + quad*4 + r for node = r16
    float4 sa = *(const float4*)(asrc + ot * 16 + quad * 4);
    float4 da = *(const float4*)(adst + ot * 16 + quad * 4);
    const int hh = ot >> 1;
    asp[hh] += acc[0] * sa.x + acc[1] * sa.y + acc[2] * sa.z + acc[3] * sa.w;
    adp[hh] += acc[0] * da.x + acc[1] * da.y + acc[2] * da.z + acc[3] * da.w;
    // h1b store: 4 consecutive channels -> one 8B store
    unsigned short* o = h1b + (size_t)node * 128 + ot * 16 + quad * 4;
    unsigned int p01 = (unsigned int)f2bf(acc[0]) | ((unsigned int)f2bf(acc[1]) << 16);
    unsigned int p23 = (unsigned int)f2bf(acc[2]) | ((unsigned int)f2bf(acc[3]) << 16);
    *(uint2*)o = make_uint2(p01, p23);
  }
  // reduce per-head partials across the 4 quads of this node (lanes r16, +16, +32, +48)
#pragma unroll
  for (int h = 0; h < 4; ++h) {
    asp[h] += __shfl_xor(asp[h], 16, 64);
    asp[h] += __shfl_xor(asp[h], 32, 64);
    adp[h] += __shfl_xor(adp[h], 16, 64);
    adp[h] += __shfl_xor(adp[h], 32, 64);
  }
  if (lane < 16) {   // coalesced 16-lane float4 stores
    as1[node] = make_float4(asp[0], asp[1], asp[2], asp[3]);
    ad1[node] = make_float4(adp[0], adp[1], adp[2], adp[3]);
  }
}

// ------- layer-1 aggregation: 4 nodes/wave, 16 lanes/node, uint4 gathers, unroll-8 -------
__global__ __launch_bounds__(256, 6) void k_agg1(
    const unsigned short* __restrict__ h1b, const float* __restrict__ as1,
    const float* __restrict__ ad1, const int* __restrict__ rowptr,
    const int* __restrict__ col, const float* __restrict__ b1,
    const float* __restrict__ W2, const float* __restrict__ asrc2,
    const float* __restrict__ adst2, float4* __restrict__ node2) {
  int wid = threadIdx.x >> 6, lane = threadIdx.x & 63;
  int grp = lane >> 4, l16 = lane & 15;
  int node = blockIdx.x * 16 + wid * 4 + grp;   // exact: 6250*16 = NN
  int head = l16 >> 2;
  float ad = ad1[node * 4 + head];
  int beg = rowptr[node], deg = rowptr[node + 1] - beg;
  const uint4* h1q = (const uint4*)h1b;         // row stride 16 uint4
  float acc[8] = {0.f, 0.f, 0.f, 0.f, 0.f, 0.f, 0.f, 0.f};
  float wsum = 0.f;
  int j = 0;
  while (__ballot(j < deg)) {
    bool a[8]; int s[8];
#pragma unroll
    for (int k = 0; k < 8; ++k) {
      a[k] = (j + k) < deg;
      s[k] = a[k] ? col[beg + j + k] : 0;
    }
    float e[8]; uint4 u[8];
#pragma unroll
    for (int k = 0; k < 8; ++k) e[k] = as1[s[k] * 4 + head] + ad;
#pragma unroll
    for (int k = 0; k < 8; ++k) u[k] = h1q[(size_t)s[k] * 16 + l16];
#pragma unroll
    for (int k = 0; k < 8; ++k) {
      float t = e[k];
      t = (t < 0.f) ? 0.2f * t : t;
      float w = a[k] ? __expf(fminf(t, 80.f)) : 0.f;
      wsum += w;
      acc[0] += w * blo(u[k].x); acc[1] += w * bhi(u[k].x);
      acc[2] += w * blo(u[k].y); acc[3] += w * bhi(u[k].y);
      acc[4] += w * blo(u[k].z); acc[5] += w * bhi(u[k].z);
      acc[6] += w * blo(u[k].w); acc[7] += w * bhi(u[k].w);
    }
    j += 8;
  }
  float inv = 1.f / (wsum + 1e-16f);
  int cb = l16 * 8;
  float h[8];
#pragma unroll
  for (int t = 0; t < 8; ++t) {
    float v = acc[t] * inv + b1[cb + t];
    h[t] = (v < 0.f) ? 0.01f * v : v;
  }
  float p0 = 0.f, p1 = 0.f;
#pragma unroll
  for (int t = 0; t < 8; ++t) {
    p0 += h[t] * W2[cb + t];
    p1 += h[t] * W2[128 + cb + t];
  }
  p0 += __shfl_xor(p0, 1, 64); p0 += __shfl_xor(p0, 2, 64);
  p0 += __shfl_xor(p0, 4, 64); p0 += __shfl_xor(p0, 8, 64);
  p1 += __shfl_xor(p1, 1, 64); p1 += __shfl_xor(p1, 2, 64);
  p1 += __shfl_xor(p1, 4, 64); p1 += __shfl_xor(p1, 8, 64);
  if (l16 == 0) {
    float as2 = p0 * asrc2[0] + p1 * asrc2[1];
    float ad2 = p0 * adst2[0] + p1 * adst2[1];
    node2[node] = make_float4(p0, p1, as2, ad2);
  }
}

// ---------------- layer-2 aggregation + log_softmax (8 lanes per node) ----------------
__global__ void k_agg2(const float4* __restrict__ node2, const int* __restrict__ rowptr,
                       const int* __restrict__ col, const float* __restrict__ b2,
                       float2* __restrict__ out) {
  int t = blockIdx.x * 256 + threadIdx.x;
  int node = t >> 3, sub = t & 7;
  if (node >= NN) return;
  float ad2 = node2[node].w;
  int beg = rowptr[node], end = rowptr[node + 1];
  float den = 0.f, a0 = 0.f, a1 = 0.f;
  for (int j = beg + sub; j < end; j += 8) {
    int s = col[j];
    float4 sv = node2[s];
    float e = sv.z + ad2;
    e = (e < 0.f) ? 0.2f * e : e;
    float w = __expf(fminf(e, 80.f));
    den += w;
    a0 += w * sv.x;
    a1 += w * sv.y;
  }
#pragma unroll
  for (int d = 1; d < 8; d <<= 1) {
    den += __shfl_xor(den, d, 64);
    a0 += __shfl_xor(a0, d, 64);
    a1 += __shfl_xor(a1, d, 64);
  }
  if (sub == 0) {
    float inv = 1.f / (den + 1e-16f);
    float o0 = a0 * inv + b2[0];
    float o1 = a1 * inv + b2[1];
    float m = fmaxf(o0, o1);
    float lse = m + __logf(__expf(o0 - m) + __expf(o1 - m));
    out[node] = make_float2(o0 - lse, o1 - lse);
  }
}

extern "C" void kernel_launch(void* const* d_in, const int* in_sizes, int n_in,
                              void* d_out, int out_size, void* d_ws, size_t ws_size,
                              hipStream_t stream) {
  const float* x     = (const float*)d_in[0];
  const int*   ei    = (const int*)d_in[1];
  const float* W1    = (const float*)d_in[2];
  const float* asrc1 = (const float*)d_in[3];
  const float* adst1 = (const float*)d_in[4];
  const float* b1    = (const float*)d_in[5];
  const float* W2    = (const float*)d_in[6];
  const float* asrc2 = (const float*)d_in[7];
  const float* adst2 = (const float*)d_in[8];
  const float* b2    = (const float*)d_in[9];
  float2* out = (float2*)d_out;

  int* rowptr     = (int*)d_ws;                    // 100352
  int* col        = rowptr + 100352;               // 1700096
  int* pair       = col + 1700096;                 // 1600000
  int* cntMat     = pair + 1600000;                // NCH*NB = 611524, pad 611584
  int* bucketCnt  = cntMat + 611584;               // 1024
  int* pairOffset = bucketCnt + 1024;              // 1024
  unsigned short* h1b = (unsigned short*)(pairOffset + 1024);  // NN*128 bf16
  float*  as1  = (float*)(h1b + (size_t)NN * 128); // NN*4
  float*  ad1  = as1 + NN * 4;                     // NN*4
  float4* node2 = (float4*)(ad1 + NN * 4);         // NN
  unsigned short* W1h = (unsigned short*)(node2 + NN);  // 16384 (packed)
  unsigned short* W1l = W1h + 16384;                    // 16384 (packed)

  kb_hist<<<NCH, 512, 0, stream>>>(ei, cntMat);
  kb_colscan<<<NB, 64, 0, stream>>>(cntMat, bucketCnt);
  kb_scan<<<1, 64, 0, stream>>>(bucketCnt, pairOffset);
  kb_scatA<<<NCH, 512, 0, stream>>>(ei, pairOffset, cntMat, pair);
  kb_binB<<<NB, 256, 0, stream>>>(pair, pairOffset, rowptr, col);
  k_cvtW<<<64, 256, 0, stream>>>(W1, W1h, W1l);
  k_gemm1<<<(NN / 16 + 3) / 4, 256, 0, stream>>>(x, W1h, W1l, asrc1, adst1, h1b,
                                                 (float4*)as1, (float4*)ad1);
  k_agg1<<<NN / 16, 256, 0, stream>>>(h1b, as1, ad1, rowptr, col, b1, W2, asrc2, adst2, node2);
  k_agg2<<<(NN * 8 + 255) / 256, 256, 0, stream>>>(node2, rowptr, col, b2, out);
}

// Round 12
// 246.881 us; speedup vs baseline: 1.0435x; 1.0435x over previous
//
#include <hip/hip_runtime.h>

#define NN 100000
#define NE 1600000
#define NTOT (NN + NE)
#define NB 782            // buckets of 128 dst nodes
#define ACHUNK 4096       // edges per chunk (hist/scatA block)
#define NCH 391           // ceil(NE/ACHUNK)
#define BCAP 3072         // phase-B LDS col capacity
#define G1SPLIT 940       // gemm blocks in K4 (rest in K5); total gemm blocks = 1563

typedef __attribute__((ext_vector_type(8))) short bf16x8;
typedef __attribute__((ext_vector_type(4))) float f32x4;

static __device__ __forceinline__ float blo(unsigned int u) {
  union { unsigned int i; float f; } v; v.i = u << 16; return v.f;
}
static __device__ __forceinline__ float bhi(unsigned int u) {
  union { unsigned int i; float f; } v; v.i = u & 0xffff0000u; return v.f;
}
static __device__ __forceinline__ unsigned short f2bf(float f) {
  union { float f; unsigned int i; } v; v.f = f;
  unsigned int i = v.i;
  i += 0x7fffu + ((i >> 16) & 1u);
  return (unsigned short)(i >> 16);
}

// ---------------- K1: per-chunk histogram  ∪  W1 split+repack ----------------
__global__ __launch_bounds__(512) void k_histcvt(const int* __restrict__ ei,
                                                 int* __restrict__ cntMat,
                                                 const float* __restrict__ W1,
                                                 unsigned short* __restrict__ Whp,
                                                 unsigned short* __restrict__ Wlp) {
  __shared__ int h[NB];
  int tid = threadIdx.x;
  if (blockIdx.x < NCH) {
    int blk = blockIdx.x;
    int e0 = blk * ACHUNK;
    int n = min(ACHUNK, NE - e0);
    for (int i = tid; i < NB; i += 512) h[i] = 0;
    __syncthreads();
    for (int i = tid; i < n; i += 512) atomicAdd(&h[ei[NE + e0 + i] >> 7], 1);
    __syncthreads();
    for (int i = tid; i < NB; i += 512) cntMat[blk * NB + i] = h[i];
  } else {
    // W repack: ((ot*4 + c)*64 + quad*16 + r16)*8 + j for W[row=ot*16+r16][k=c*32+quad*8+j]
    int i = (blockIdx.x - NCH) * 512 + tid;
    if (i < 128 * 128) {
      int row = i >> 7, k = i & 127;
      int ot = row >> 4, r16 = row & 15;
      int c = k >> 5, quad = (k >> 3) & 3, j = k & 7;
      int dst = ((ot * 4 + c) * 64 + quad * 16 + r16) * 8 + j;
      float v = W1[i];
      unsigned short hh = f2bf(v);
      Whp[dst] = hh;
      Wlp[dst] = f2bf(v - blo((unsigned int)hh));
    }
  }
}

__global__ void kb_colscan(int* __restrict__ cntMat, int* __restrict__ bucketCnt) {
  int b = blockIdx.x;
  int lane = threadIdx.x;  // 64
  int carry = 0;
  for (int base = 0; base < NCH; base += 64) {
    int idx = base + lane;
    int v = (idx < NCH) ? cntMat[idx * NB + b] : 0;
    int x = v;
#pragma unroll
    for (int d = 1; d < 64; d <<= 1) {
      int y = __shfl_up(x, d, 64);
      if (lane >= d) x += y;
    }
    if (idx < NCH) cntMat[idx * NB + b] = carry + x - v;  // exclusive within column
    carry += __shfl(x, 63, 64);
  }
  if (lane == 0) bucketCnt[b] = carry;
}

__global__ void kb_scan(const int* __restrict__ bucketCnt, int* __restrict__ pairOffset) {
  int lane = threadIdx.x;  // 64 threads, 13 chunks each
  int c[13];
  int run = 0;
  int idx0 = lane * 13;
#pragma unroll
  for (int k = 0; k < 13; ++k) {
    int idx = idx0 + k;
    int v = (idx < NB) ? bucketCnt[idx] : 0;
    c[k] = run;
    run += v;
  }
  int x = run;
#pragma unroll
  for (int d = 1; d < 64; d <<= 1) {
    int y = __shfl_up(x, d, 64);
    if (lane >= d) x += y;
  }
  int laneoff = x - run;
#pragma unroll
  for (int k = 0; k < 13; ++k) {
    int idx = idx0 + k;
    if (idx <= NB) pairOffset[idx] = laneoff + c[k];
  }
}

// ---------------- role bodies ----------------
static __device__ __forceinline__ void scat_role(char* smem, int blk,
                                                 const int* __restrict__ ei,
                                                 const int* __restrict__ pairOffset,
                                                 const int* __restrict__ cntMat,
                                                 int* __restrict__ pair) {
  int* lcnt = (int*)smem;          // NB+1
  int* gbase = lcnt + (NB + 1);    // NB
  int* lcur = gbase + NB;          // NB
  int* stage = lcur + NB;          // ACHUNK
  int tid = threadIdx.x;
  int e0 = blk * ACHUNK;
  int n = min(ACHUNK, NE - e0);
  for (int i = tid; i <= NB; i += 512) lcnt[i] = 0;
  __syncthreads();
  for (int i = tid; i < n; i += 512) atomicAdd(&lcnt[ei[NE + e0 + i] >> 7], 1);
  __syncthreads();
  if (tid < 64) {
    int c[13];
    int run = 0;
    int idx0 = tid * 13;
#pragma unroll
    for (int k = 0; k < 13; ++k) {
      int idx = idx0 + k;
      int v = (idx < NB) ? lcnt[idx] : 0;
      c[k] = run;
      run += v;
    }
    int x = run;
#pragma unroll
    for (int d = 1; d < 64; d <<= 1) {
      int y = __shfl_up(x, d, 64);
      if (tid >= d) x += y;
    }
    int laneoff = x - run;
#pragma unroll
    for (int k = 0; k < 13; ++k) {
      int idx = idx0 + k;
      if (idx <= NB) lcnt[idx] = laneoff + c[k];
    }
  }
  __syncthreads();
  for (int b = tid; b < NB; b += 512) {
    gbase[b] = pairOffset[b] + cntMat[blk * NB + b];  // no global atomics
    lcur[b] = lcnt[b];
  }
  __syncthreads();
  for (int i = tid; i < n; i += 512) {
    int s = ei[e0 + i], d = ei[NE + e0 + i];
    int b = d >> 7;
    int p = atomicAdd(&lcur[b], 1);   // LDS only
    stage[p] = (s << 7) | (d & 127);
  }
  __syncthreads();
  for (int b = tid; b < NB; b += 512) {
    int base = lcnt[b], cnt = lcnt[b + 1] - base, g = gbase[b];
    for (int k = 0; k < cnt; ++k) pair[g + k] = stage[base + k];
  }
}

static __device__ __forceinline__ void bin_role(char* smem, int b,
                                                const int* __restrict__ pair,
                                                const int* __restrict__ pairOffset,
                                                int* __restrict__ rowptr,
                                                int* __restrict__ col) {
  int* cnt = (int*)smem;       // 128
  int* cur = cnt + 128;        // 128
  int* stage = cur + 128;      // BCAP
  int tid = threadIdx.x;
  int dbase = b << 7;
  int nd = min(128, NN - dbase);
  int pbeg = pairOffset[b], m = pairOffset[b + 1] - pbeg;
  int cbase = pbeg + dbase;
  if (tid < 128) cnt[tid] = 0;
  __syncthreads();
  for (int i = tid; i < m; i += 256) atomicAdd(&cnt[pair[pbeg + i] & 127], 1);
  __syncthreads();
  if (tid < 64) {
    int i0 = 2 * tid, i1 = 2 * tid + 1;
    int v0 = cnt[i0] + (i0 < nd ? 1 : 0);
    int v1 = cnt[i1] + (i1 < nd ? 1 : 0);
    int run = v0 + v1;
    int x = run;
#pragma unroll
    for (int d = 1; d < 64; d <<= 1) {
      int y = __shfl_up(x, d, 64);
      if (tid >= d) x += y;
    }
    int e0 = x - run;
    int e1 = e0 + v0;
    if (i0 < nd) { rowptr[dbase + i0] = cbase + e0; stage[e0] = dbase + i0; cur[i0] = e0 + 1; }
    else cur[i0] = e0;
    if (i1 < nd) { rowptr[dbase + i1] = cbase + e1; stage[e1] = dbase + i1; cur[i1] = e1 + 1; }
    else cur[i1] = e1;
  }
  if (b == NB - 1 && tid == 0) rowptr[NN] = NTOT;
  __syncthreads();
  for (int i = tid; i < m; i += 256) {
    int p = pair[pbeg + i];
    int pos = atomicAdd(&cur[p & 127], 1);
    stage[pos] = p >> 7;
  }
  __syncthreads();
  int tot = m + nd;
  for (int i = tid; i < tot; i += 256) col[cbase + i] = stage[i];
}

// gemm role: operand-swapped MFMA GEMM, A=W (packed), B=x (LDS tile). Uses tid<256 only.
static __device__ __forceinline__ void gemm_role(char* smem, int gblk,
    const float* __restrict__ x, const unsigned short* __restrict__ Whp,
    const unsigned short* __restrict__ Wlp, const float* __restrict__ asrc,
    const float* __restrict__ adst, unsigned short* __restrict__ h1b,
    float4* __restrict__ as1, float4* __restrict__ ad1) {
  int wid = threadIdx.x >> 6, lane = threadIdx.x & 63;
  int tile = gblk * 4 + wid;
  if (tile >= NN / 16) tile = NN / 16 - 1;  // clamp: duplicate work, benign
  float* xs = (float*)smem + wid * (16 * 129);
  int r16 = lane & 15, quad = lane >> 4;
  const float4* xg = (const float4*)(x + (size_t)tile * 16 * 128);
  {
    int half = lane >> 5, l32 = lane & 31;
#pragma unroll
    for (int i = 0; i < 8; ++i) {
      int row = i * 2 + half;
      float4 v = xg[row * 32 + l32];
      float* dp = &xs[row * 129 + l32 * 4];
      dp[0] = v.x; dp[1] = v.y; dp[2] = v.z; dp[3] = v.w;
    }
  }
  bf16x8 bh[4], bl[4];
  const float* xr = &xs[r16 * 129 + quad * 8];
#pragma unroll
  for (int c = 0; c < 4; ++c) {
#pragma unroll
    for (int j = 0; j < 8; ++j) {
      float v = xr[c * 32 + j];
      union { float f; unsigned int i; } u; u.f = v;
      bh[c][j] = (short)(u.i >> 16);
      union { float f; unsigned int i; } l; l.f = v - bhi(u.i);
      bl[c][j] = (short)(l.i >> 16);
    }
  }
  float asp[4] = {0.f, 0.f, 0.f, 0.f};
  float adp[4] = {0.f, 0.f, 0.f, 0.f};
  int node = tile * 16 + r16;
#pragma unroll
  for (int ot = 0; ot < 8; ++ot) {
    f32x4 acc = {0.f, 0.f, 0.f, 0.f};
#pragma unroll
    for (int c = 0; c < 4; ++c) {
      const bf16x8 wh = *(const bf16x8*)(Whp + ((size_t)(ot * 4 + c) * 64 + lane) * 8);
      const bf16x8 wl = *(const bf16x8*)(Wlp + ((size_t)(ot * 4 + c) * 64 + lane) * 8);
      acc = __builtin_amdgcn_mfma_f32_16x16x32_bf16(wh, bh[c], acc, 0, 0, 0);
      acc = __builtin_amdgcn_mfma_f32_16x16x32_bf16(wl, bh[c], acc, 0, 0, 0);
      acc = __builtin_amdgcn_mfma_f32_16x16x32_bf16(wh, bl[c], acc, 0, 0, 0);
    }
    float4 sa = *(const float4*)(asrc + ot * 16 + quad * 4);
    float4 da = *(const float4*)(adst + ot * 16 + quad * 4);
    const int hh = ot >> 1;
    asp[hh] += acc[0] * sa.x + acc[1] * sa.y + acc[2] * sa.z + acc[3] * sa.w;
    adp[hh] += acc[0] * da.x + acc[1] * da.y + acc[2] * da.z + acc[3] * da.w;
    unsigned short* o = h1b + (size_t)node * 128 + ot * 16 + quad * 4;
    unsigned int p01 = (unsigned int)f2bf(acc[0]) | ((unsigned int)f2bf(acc[1]) << 16);
    unsigned int p23 = (unsigned int)f2bf(acc[2]) | ((unsigned int)f2bf(acc[3]) << 16);
    *(uint2*)o = make_uint2(p01, p23);
  }
#pragma unroll
  for (int h = 0; h < 4; ++h) {
    asp[h] += __shfl_xor(asp[h], 16, 64);
    asp[h] += __shfl_xor(asp[h], 32, 64);
    adp[h] += __shfl_xor(adp[h], 16, 64);
    adp[h] += __shfl_xor(adp[h], 32, 64);
  }
  if (lane < 16) {
    as1[node] = make_float4(asp[0], asp[1], asp[2], asp[3]);
    ad1[node] = make_float4(adp[0], adp[1], adp[2], adp[3]);
  }
}

// ---------------- K4: scatA ∪ gemm1 part 1 ----------------
__global__ __launch_bounds__(512) void k_scatgemm(
    const int* __restrict__ ei, const int* __restrict__ pairOffset,
    const int* __restrict__ cntMat, int* __restrict__ pair,
    const float* __restrict__ x, const unsigned short* __restrict__ Whp,
    const unsigned short* __restrict__ Wlp, const float* __restrict__ asrc,
    const float* __restrict__ adst, unsigned short* __restrict__ h1b,
    float4* __restrict__ as1, float4* __restrict__ ad1) {
  __shared__ __align__(16) char smem[33024];
  if (blockIdx.x < NCH) {
    scat_role(smem, blockIdx.x, ei, pairOffset, cntMat, pair);
    return;
  }
  if (threadIdx.x >= 256) return;   // gemm role uses 4 waves; no barriers inside
  gemm_role(smem, blockIdx.x - NCH, x, Whp, Wlp, asrc, adst, h1b, as1, ad1);
}

// ---------------- K5: binB ∪ gemm1 part 2 ----------------
__global__ __launch_bounds__(256) void k_bingemm(
    const int* __restrict__ pair, const int* __restrict__ pairOffset,
    int* __restrict__ rowptr, int* __restrict__ col,
    const float* __restrict__ x, const unsigned short* __restrict__ Whp,
    const unsigned short* __restrict__ Wlp, const float* __restrict__ asrc,
    const float* __restrict__ adst, unsigned short* __restrict__ h1b,
    float4* __restrict__ as1, float4* __restrict__ ad1) {
  __shared__ __align__(16) char smem[33024];
  if (blockIdx.x < NB) {
    bin_role(smem, blockIdx.x, pair, pairOffset, rowptr, col);
    return;
  }
  gemm_role(smem, G1SPLIT + (int)blockIdx.x - NB, x, Whp, Wlp, asrc, adst, h1b, as1, ad1);
}

// ------- layer-1 aggregation: 4 nodes/wave, 16 lanes/node, uint4 gathers, unroll-8 -------
__global__ __launch_bounds__(256, 6) void k_agg1(
    const unsigned short* __restrict__ h1b, const float* __restrict__ as1,
    const float* __restrict__ ad1, const int* __restrict__ rowptr,
    const int* __restrict__ col, const float* __restrict__ b1,
    const float* __restrict__ W2, const float* __restrict__ asrc2,
    const float* __restrict__ adst2, float4* __restrict__ node2) {
  int wid = threadIdx.x >> 6, lane = threadIdx.x & 63;
  int grp = lane >> 4, l16 = lane & 15;
  int node = blockIdx.x * 16 + wid * 4 + grp;   // exact: 6250*16 = NN
  int head = l16 >> 2;
  float ad = ad1[node * 4 + head];
  int beg = rowptr[node], deg = rowptr[node + 1] - beg;
  const uint4* h1q = (const uint4*)h1b;         // row stride 16 uint4
  float acc[8] = {0.f, 0.f, 0.f, 0.f, 0.f, 0.f, 0.f, 0.f};
  float wsum = 0.f;
  int j = 0;
  while (__ballot(j < deg)) {
    bool a[8]; int s[8];
#pragma unroll
    for (int k = 0; k < 8; ++k) {
      a[k] = (j + k) < deg;
      s[k] = a[k] ? col[beg + j + k] : 0;
    }
    float e[8]; uint4 u[8];
#pragma unroll
    for (int k = 0; k < 8; ++k) e[k] = as1[s[k] * 4 + head] + ad;
#pragma unroll
    for (int k = 0; k < 8; ++k) u[k] = h1q[(size_t)s[k] * 16 + l16];
#pragma unroll
    for (int k = 0; k < 8; ++k) {
      float t = e[k];
      t = (t < 0.f) ? 0.2f * t : t;
      float w = a[k] ? __expf(fminf(t, 80.f)) : 0.f;
      wsum += w;
      acc[0] += w * blo(u[k].x); acc[1] += w * bhi(u[k].x);
      acc[2] += w * blo(u[k].y); acc[3] += w * bhi(u[k].y);
      acc[4] += w * blo(u[k].z); acc[5] += w * bhi(u[k].z);
      acc[6] += w * blo(u[k].w); acc[7] += w * bhi(u[k].w);
    }
    j += 8;
  }
  float inv = 1.f / (wsum + 1e-16f);
  int cb = l16 * 8;
  float h[8];
#pragma unroll
  for (int t = 0; t < 8; ++t) {
    float v = acc[t] * inv + b1[cb + t];
    h[t] = (v < 0.f) ? 0.01f * v : v;
  }
  float p0 = 0.f, p1 = 0.f;
#pragma unroll
  for (int t = 0; t < 8; ++t) {
    p0 += h[t] * W2[cb + t];
    p1 += h[t] * W2[128 + cb + t];
  }
  p0 += __shfl_xor(p0, 1, 64); p0 += __shfl_xor(p0, 2, 64);
  p0 += __shfl_xor(p0, 4, 64); p0 += __shfl_xor(p0, 8, 64);
  p1 += __shfl_xor(p1, 1, 64); p1 += __shfl_xor(p1, 2, 64);
  p1 += __shfl_xor(p1, 4, 64); p1 += __shfl_xor(p1, 8, 64);
  if (l16 == 0) {
    float as2 = p0 * asrc2[0] + p1 * asrc2[1];
    float ad2 = p0 * adst2[0] + p1 * adst2[1];
    node2[node] = make_float4(p0, p1, as2, ad2);
  }
}

// ---------------- layer-2 aggregation + log_softmax (8 lanes per node) ----------------
__global__ void k_agg2(const float4* __restrict__ node2, const int* __restrict__ rowptr,
                       const int* __restrict__ col, const float* __restrict__ b2,
                       float2* __restrict__ out) {
  int t = blockIdx.x * 256 + threadIdx.x;
  int node = t >> 3, sub = t & 7;
  if (node >= NN) return;
  float ad2 = node2[node].w;
  int beg = rowptr[node], end = rowptr[node + 1];
  float den = 0.f, a0 = 0.f, a1 = 0.f;
  for (int j = beg + sub; j < end; j += 8) {
    int s = col[j];
    float4 sv = node2[s];
    float e = sv.z + ad2;
    e = (e < 0.f) ? 0.2f * e : e;
    float w = __expf(fminf(e, 80.f));
    den += w;
    a0 += w * sv.x;
    a1 += w * sv.y;
  }
#pragma unroll
  for (int d = 1; d < 8; d <<= 1) {
    den += __shfl_xor(den, d, 64);
    a0 += __shfl_xor(a0, d, 64);
    a1 += __shfl_xor(a1, d, 64);
  }
  if (sub == 0) {
    float inv = 1.f / (den + 1e-16f);
    float o0 = a0 * inv + b2[0];
    float o1 = a1 * inv + b2[1];
    float m = fmaxf(o0, o1);
    float lse = m + __logf(__expf(o0 - m) + __expf(o1 - m));
    out[node] = make_float2(o0 - lse, o1 - lse);
  }
}

extern "C" void kernel_launch(void* const* d_in, const int* in_sizes, int n_in,
                              void* d_out, int out_size, void* d_ws, size_t ws_size,
                              hipStream_t stream) {
  const float* x     = (const float*)d_in[0];
  const int*   ei    = (const int*)d_in[1];
  const float* W1    = (const float*)d_in[2];
  const float* asrc1 = (const float*)d_in[3];
  const float* adst1 = (const float*)d_in[4];
  const float* b1    = (const float*)d_in[5];
  const float* W2    = (const float*)d_in[6];
  const float* asrc2 = (const float*)d_in[7];
  const float* adst2 = (const float*)d_in[8];
  const float* b2    = (const float*)d_in[9];
  float2* out = (float2*)d_out;

  int* rowptr     = (int*)d_ws;                    // 100352
  int* col        = rowptr + 100352;               // 1700096
  int* pair       = col + 1700096;                 // 1600000
  int* cntMat     = pair + 1600000;                // NCH*NB = 305762, pad 305792
  int* bucketCnt  = cntMat + 305792;               // 1024
  int* pairOffset = bucketCnt + 1024;              // 1024
  unsigned short* h1b = (unsigned short*)(pairOffset + 1024);  // NN*128 bf16
  float*  as1  = (float*)(h1b + (size_t)NN * 128); // NN*4
  float*  ad1  = as1 + NN * 4;                     // NN*4
  float4* node2 = (float4*)(ad1 + NN * 4);         // NN
  unsigned short* W1h = (unsigned short*)(node2 + NN);  // 16384 (packed)
  unsigned short* W1l = W1h + 16384;                    // 16384 (packed)

  // K1: histogram (391 blocks) ∪ W repack (32 blocks)
  k_histcvt<<<NCH + 32, 512, 0, stream>>>(ei, cntMat, W1, W1h, W1l);
  kb_colscan<<<NB, 64, 0, stream>>>(cntMat, bucketCnt);
  kb_scan<<<1, 64, 0, stream>>>(bucketCnt, pairOffset);
  // K4: edge bucket-sort (391 blocks) ∪ gemm tiles [0, G1SPLIT)
  k_scatgemm<<<NCH + G1SPLIT, 512, 0, stream>>>(ei, pairOffset, cntMat, pair,
                                                x, W1h, W1l, asrc1, adst1, h1b,
                                                (float4*)as1, (float4*)ad1);
  // K5: CSR placement (782 blocks) ∪ gemm tiles [G1SPLIT, 1563)
  k_bingemm<<<NB + (1563 - G1SPLIT), 256, 0, stream>>>(pair, pairOffset, rowptr, col,
                                                       x, W1h, W1l, asrc1, adst1, h1b,
                                                       (float4*)as1, (float4*)ad1);
  k_agg1<<<NN / 16, 256, 0, stream>>>(h1b, as1, ad1, rowptr, col, b1, W2, asrc2, adst2, node2);
  k_agg2<<<(NN * 8 + 255) / 256, 256, 0, stream>>>(node2, rowptr, col, b2, out);
}